// Round 7
// baseline (449.918 us; speedup 1.0000x reference)
//
#include <hip/hip_runtime.h>

namespace {

constexpr int T = 512, B = 128, I = 64, H = 512, R = 8;
constexpr int CH = 16;          // time steps per x_proj chunk
constexpr int NCH = T / CH;     // 32
constexpr float ALPHA = 0.1f;

typedef _Float16 f16x8 __attribute__((ext_vector_type(8)));
typedef float f32x4 __attribute__((ext_vector_type(4)));

// DPP move: value of x taken from lane given by ctrl (bound_ctrl=1, all rows/banks)
#define DPPF(x, ctrl) \
  __int_as_float(__builtin_amdgcn_update_dpp(0, __float_as_int(x), (ctrl), 0xF, 0xF, true))
// quad_perm xor1 -> 0xB1 ; quad_perm xor2 -> 0x4E
// row_half_mirror (lane^7 within 8) -> 0x141 ; row_ror:8 (lane^8 within 16) -> 0x128

// One wave per batch element: 64 lanes x 8 hidden units each; no barriers,
// no cross-wave traffic. Rank-8 reduction is a wave-internal DPP/shfl tree.
__global__ __launch_bounds__(64, 1)
void ctrnn(const float* __restrict__ input, const float* __restrict__ W_in,
           const float* __restrict__ b_in, const float* __restrict__ U,
           const float* __restrict__ V, const float* __restrict__ noise,
           float* __restrict__ out) {
  const int b = blockIdx.x;       // batch element
  const int L = threadIdx.x;      // lane 0..63; owns h = 8L..8L+7

  // LDS: W fp16 swizzled [h][i ^ ((h&7)<<3)] = 64KB; xp fp32 [16][512] = 32KB
  __shared__ __align__(16) _Float16 Wl[H * I];
  __shared__ __align__(16) float xp[CH * H];

  // ---- one-time: stage W_in -> LDS fp16 (swizzled for conflict-light B-frag reads)
  for (int rr = 0; rr < 64; ++rr) {
    const int bid = rr * 64 + L;          // 4096 8-element blocks
    const int h = bid >> 3, ib = (bid & 7) * 8;
    const float* src = W_in + h * I + ib;
    const float4 lo = *(const float4*)src;
    const float4 hi = *(const float4*)(src + 4);
    f16x8 v;
    v[0] = (_Float16)lo.x; v[1] = (_Float16)lo.y; v[2] = (_Float16)lo.z; v[3] = (_Float16)lo.w;
    v[4] = (_Float16)hi.x; v[5] = (_Float16)hi.y; v[6] = (_Float16)hi.z; v[7] = (_Float16)hi.w;
    *(f16x8*)&Wl[h * I + (ib ^ ((h & 7) << 3))] = v;
  }

  // per-lane slot->r mapping: slot j holds r = j ^ m (select-free DPP folds)
  int m = ((L & 1) << 2) | (L & 2);
  if (L & 4) m ^= 7;

  // V fragments: Vr[j][k] = V[j^m][8L+k]; U gathered to match g-slot order
  // g-slot r-values after gather: {m, m^4, m^2, m^6, m^1, m^5, m^3, m^7}
  const int ss[8] = {0, 4, 2, 6, 1, 5, 3, 7};
  float Vr[8][8], Up[8][8], bia[8], hs[8];
#pragma unroll
  for (int j = 0; j < 8; ++j)
#pragma unroll
    for (int k = 0; k < 8; ++k) Vr[j][k] = V[(j ^ m) * H + 8 * L + k];
#pragma unroll
  for (int k = 0; k < 8; ++k) {
    bia[k] = b_in[8 * L + k];
    hs[k] = 0.f;
#pragma unroll
    for (int j = 0; j < 8; ++j) Up[k][j] = U[(8 * L + k) * R + (m ^ ss[j])];
  }

  const int BH = B * H;
  const float* nz_b = noise + b * H + 8 * L;
  float* out_b = out + b * H + 8 * L;

  // ---- noise register ring, 4 steps deep (32B/lane/step, coalesced)
  float4 nb0[4], nb1[4];
#pragma unroll
  for (int s = 0; s < 4; ++s) {
    nb0[s] = *(const float4*)(nz_b + s * BH);
    nb1[s] = *(const float4*)(nz_b + s * BH + 4);
  }

  // ---- input prefetch for chunk 0 (A-operand of x_proj MFMA)
  const int trow = L & 15, krow = (L >> 4) * 8;
  float av[2][8];
#pragma unroll
  for (int kt = 0; kt < 2; ++kt) {
    const float* src = input + (trow * B + b) * I + kt * 32 + krow;
    const float4 lo = *(const float4*)src;
    const float4 hi = *(const float4*)(src + 4);
    av[kt][0] = lo.x; av[kt][1] = lo.y; av[kt][2] = lo.z; av[kt][3] = lo.w;
    av[kt][4] = hi.x; av[kt][5] = hi.y; av[kt][6] = hi.z; av[kt][7] = hi.w;
  }

  for (int c = 0; c < NCH; ++c) {
    // ---- x_proj chunk via MFMA: xp[16t][512h] = in[16x64] @ W^T, fp32 out
    f16x8 af0, af1;
#pragma unroll
    for (int j = 0; j < 8; ++j) { af0[j] = (_Float16)av[0][j]; af1[j] = (_Float16)av[1][j]; }
#pragma unroll
    for (int nt = 0; nt < 32; ++nt) {
      const int h0 = nt * 16 + trow;
      const int sw = (h0 & 7) << 3;
      const f16x8 b0 = *(const f16x8*)&Wl[h0 * I + (krow ^ sw)];
      const f16x8 b1 = *(const f16x8*)&Wl[h0 * I + ((32 + krow) ^ sw)];
      f32x4 acc = {0.f, 0.f, 0.f, 0.f};
      acc = __builtin_amdgcn_mfma_f32_16x16x32_f16(af0, b0, acc, 0, 0, 0);
      acc = __builtin_amdgcn_mfma_f32_16x16x32_f16(af1, b1, acc, 0, 0, 0);
#pragma unroll
      for (int q = 0; q < 4; ++q) xp[((L >> 4) * 4 + q) * H + h0] = acc[q];
    }
    // prefetch next chunk's input (consumed ~8k cycles later)
    if (c + 1 < NCH) {
#pragma unroll
      for (int kt = 0; kt < 2; ++kt) {
        const float* src = input + (((c + 1) * CH + trow) * B + b) * I + kt * 32 + krow;
        const float4 lo = *(const float4*)src;
        const float4 hi = *(const float4*)(src + 4);
        av[kt][0] = lo.x; av[kt][1] = lo.y; av[kt][2] = lo.z; av[kt][3] = lo.w;
        av[kt][4] = hi.x; av[kt][5] = hi.y; av[kt][6] = hi.z; av[kt][7] = hi.w;
      }
    }

    // ---- 16 steps; unrolled x4 so the noise ring indexes statically
    const int tb = c * CH;
    for (int s4 = 0; s4 < CH; s4 += 4) {
#pragma unroll
      for (int u = 0; u < 4; ++u) {
        const int s = s4 + u, t = tb + s;
        const float4 n0 = nb0[u], n1 = nb1[u];
        int tp = t + 4; if (tp > T - 1) tp = T - 1;   // clamped, never consumed if OOB
        nb0[u] = *(const float4*)(nz_b + tp * BH);
        nb1[u] = *(const float4*)(nz_b + tp * BH + 4);
        hs[0] += n0.x; hs[1] += n0.y; hs[2] += n0.z; hs[3] += n0.w;
        hs[4] += n1.x; hs[5] += n1.y; hs[6] += n1.z; hs[7] += n1.w;
        // V-side partials: p[j] = sum_k V[j^m][h_k] * h_k  (8 indep FMA chains)
        float p[8];
#pragma unroll
        for (int j = 0; j < 8; ++j) {
          p[j] = Vr[j][0] * hs[0];
#pragma unroll
          for (int k = 1; k < 8; ++k) p[j] = fmaf(Vr[j][k], hs[k], p[j]);
        }
        // select-free folds: after 3 levels lane L holds group-partial v[m(L)]
        p[0] += DPPF(p[4], 0xB1); p[1] += DPPF(p[5], 0xB1);
        p[2] += DPPF(p[6], 0xB1); p[3] += DPPF(p[7], 0xB1);
        p[0] += DPPF(p[2], 0x4E); p[1] += DPPF(p[3], 0x4E);
        p[0] += DPPF(p[1], 0x141);
        float sg = p[0];
        sg += DPPF(sg, 0x128);          // xor8
        sg += __shfl_xor(sg, 16, 64);   // xor16
        sg += __shfl_xor(sg, 32, 64);   // xor32 -> v_total[m(L)]
        // all-gather 8 v's within 8-lane group
        float g[8];
        g[0] = sg;
        g[1] = DPPF(g[0], 0xB1); g[2] = DPPF(g[0], 0x4E); g[3] = DPPF(g[1], 0x4E);
        g[4] = DPPF(g[0], 0x141); g[5] = DPPF(g[1], 0x141);
        g[6] = DPPF(g[2], 0x141); g[7] = DPPF(g[3], 0x141);
        // xp read (fp32 LDS, 32B contiguous per lane)
        const float4 x0 = *(const float4*)&xp[s * H + 8 * L];
        const float4 x1 = *(const float4*)&xp[s * H + 8 * L + 4];
        const float xv[8] = {x0.x, x0.y, x0.z, x0.w, x1.x, x1.y, x1.z, x1.w};
        // U-side + epilogue per owned h
#pragma unroll
        for (int k = 0; k < 8; ++k) {
          float rec = Up[k][0] * g[0];
#pragma unroll
          for (int j = 1; j < 8; ++j) rec = fmaf(Up[k][j], g[j], rec);
          float hn = xv[k] + bia[k] + rec;
          hn = hn > 0.f ? hn : 0.f;
          hs[k] = fmaf(hs[k], 1.f - ALPHA, hn * ALPHA);
        }
        const float4 o0 = {hs[0], hs[1], hs[2], hs[3]};
        const float4 o1 = {hs[4], hs[5], hs[6], hs[7]};
        *(float4*)(out_b + t * BH) = o0;
        *(float4*)(out_b + t * BH + 4) = o1;
      }
    }
  }

  // hN (second tuple output)
  float* hN = out + (size_t)T * BH + b * H + 8 * L;
  const float4 o0 = {hs[0], hs[1], hs[2], hs[3]};
  const float4 o1 = {hs[4], hs[5], hs[6], hs[7]};
  *(float4*)(hN) = o0;
  *(float4*)(hN + 4) = o1;
}

}  // namespace

extern "C" void kernel_launch(void* const* d_in, const int* in_sizes, int n_in,
                              void* d_out, int out_size, void* d_ws, size_t ws_size,
                              hipStream_t stream) {
  const float* input = (const float*)d_in[0];
  const float* W_in  = (const float*)d_in[1];
  const float* b_in  = (const float*)d_in[2];
  const float* U     = (const float*)d_in[3];
  const float* V     = (const float*)d_in[4];
  const float* noise = (const float*)d_in[5];
  float* out = (float*)d_out;
  ctrnn<<<dim3(B), dim3(64), 0, stream>>>(input, W_in, b_in, U, V, noise, out);
}